// Round 13
// baseline (2024.467 us; speedup 1.0000x reference)
//
#include <hip/hip_runtime.h>
#include <hip/hip_bf16.h>
#include <cmath>

typedef unsigned int u32;
typedef unsigned short u16;
typedef _Float16 f16;
typedef f16 h2 __attribute__((ext_vector_type(2)));
typedef f16 h8 __attribute__((ext_vector_type(8)));
typedef float f32x4 __attribute__((ext_vector_type(4)));
typedef u16 u16x4 __attribute__((ext_vector_type(4)));

// ---------- sizes ----------
#define Bn 64
#define Tn 1024
#define IDIM 80
#define Hn 256
#define G3 768           // 3*H
#define STOK 5
#define SDIM 128
#define MROWS (Bn*Tn)    // 65536
#define CH 8             // steps per x-chunk

// ---------- helpers ----------
__device__ __forceinline__ u16 f2h(float f) {
  union { f16 h; u16 u; } c; c.h = (f16)f; return c.u;
}
__device__ __forceinline__ float h2f(u16 u) {
  union { f16 h; u16 u2; } c; c.u2 = u; return (float)c.h;
}
__device__ __forceinline__ float frcp(float x) {
#if __has_builtin(__builtin_amdgcn_rcpf)
  return __builtin_amdgcn_rcpf(x);
#else
  return 1.f / x;
#endif
}
__device__ __forceinline__ float fsig(float x) { return frcp(1.f + __expf(-x)); }
__device__ __forceinline__ float ftanh(float x) { return 1.f - 2.f * frcp(1.f + __expf(2.f * x)); }
// int8 dot4: c += sum of 4 signed-byte products
__device__ __forceinline__ int sdot4(u32 a, u32 b, int c) {
#if __has_builtin(__builtin_amdgcn_sdot4)
  return __builtin_amdgcn_sdot4(a, b, c, false);
#else
  int r = c;
#pragma unroll
  for (int j = 0; j < 4; ++j)
    r += (int)(char)(a >> (8 * j)) * (int)(char)(b >> (8 * j));
  return r;
#endif
}
// quad (4-lane) int sum via DPP quad_perm
__device__ __forceinline__ int qsumi(int v) {
  v += __builtin_amdgcn_mov_dpp(v, 0xB1, 0xF, 0xF, true); // xor 1
  v += __builtin_amdgcn_mov_dpp(v, 0x4E, 0xF, 0xF, true); // xor 2
  return v;
}

// LDS-only barrier: raw s_barrier so in-flight global ops survive.
__device__ __forceinline__ void lds_barrier() {
  asm volatile("s_waitcnt lgkmcnt(0)" ::: "memory");
  __builtin_amdgcn_sched_barrier(0);
  __builtin_amdgcn_s_barrier();
  __builtin_amdgcn_sched_barrier(0);
}

// ---------- conversion / prep ----------
__global__ void k_cvt_f16(const float* __restrict__ in, u16* __restrict__ out, int n) {
  int i = blockIdx.x * blockDim.x + threadIdx.x;
  int st = gridDim.x * blockDim.x;
  for (; i < n; i += st) out[i] = f2h(in[i]);
}

// per-row absmax of Whh[768][256]; wmax[j] = m, wsc[j] = m/(127*127)
__global__ void k_wmax(const float* __restrict__ W, float* __restrict__ wmax,
                       float* __restrict__ wsc) {
  int j = blockIdx.x * 256 + threadIdx.x;
  if (j >= G3) return;
  float m = 0.f;
  for (int k = 0; k < Hn; ++k) m = fmaxf(m, fabsf(W[j * Hn + k]));
  wmax[j] = m;
  wsc[j] = m * (1.f / 16129.f);
}

// Pack Whh -> int8 QUAD-OWNS-ELEMENT layout (R13):
// thread tau (0..1023): quad j = tau>>2 owns element j; lane q = tau&3 covers
// k-bytes [q*64, q*64+64). Rows are {j, j+256, j+512} (s = 0..2).
// out[tau*48 + s*16 + i] = bytes W[j+256*s][q*64 + i*4 .. +3], per-row quantized.
__global__ void k_prep_i8(const float* __restrict__ W, const float* __restrict__ wmax,
                          u32* __restrict__ out) {
  int idx = blockIdx.x * 256 + threadIdx.x;
  if (idx >= 1024 * 48) return;
  int tau = idx / 48, rest = idx % 48;
  int s = rest >> 4, i4p = rest & 15;
  int j = tau >> 2, q = tau & 3;
  int r = j + 256 * s;
  int c0 = q * 64 + i4p * 4;
  float m = wmax[r];
  float inv = (m > 0.f) ? (127.f / m) : 0.f;
  u32 pk = 0;
#pragma unroll
  for (int jj = 0; jj < 4; ++jj) {
    int qv = (int)lrintf(W[r * Hn + c0 + jj] * inv);
    qv = (qv > 127) ? 127 : (qv < -127) ? -127 : qv;
    pk |= ((u32)(unsigned char)(char)qv) << (8 * jj);
  }
  out[idx] = pk;
}

// ---------- k/v projection (f32) ----------
__global__ __launch_bounds__(256) void k_kv(const float* __restrict__ st,
                                            const float* __restrict__ kw,
                                            const float* __restrict__ vw,
                                            const float* __restrict__ inb,
                                            float* __restrict__ kv) {
  int e = threadIdx.x;
  for (int s = 0; s < STOK; ++s) {
    float ak = inb[Hn + e], av = inb[2 * Hn + e];
    for (int d = 0; d < SDIM; ++d) {
      float x = st[s * SDIM + d];
      ak += x * kw[e * SDIM + d];
      av += x * vw[e * SDIM + d];
    }
    kv[s * Hn + e] = ak;
    kv[STOK * Hn + s * Hn + e] = av;
  }
}

// ---------- standalone f16 MFMA GEMM: C = scale*(A @ B^T + bias) ----------
// MODE 0: f32 out [M][N]; 1: f16 out [M][N]; 2: f16 out TRANSPOSED [B][N][T]
template <int MODE>
__global__ __launch_bounds__(256) void k_gemm_bt(const u16* __restrict__ A,
                                                 const u16* __restrict__ B,
                                                 const float* __restrict__ bias,
                                                 float scale, void* __restrict__ Cout,
                                                 int M, int N, int K) {
  constexpr int BM = 128, BN = 128, BK = 32, LDT = 40;
  __shared__ __align__(16) u16 As[BM * LDT];
  __shared__ __align__(16) u16 Bs[BN * LDT];
  const int tid = threadIdx.x;
  const int bm0 = blockIdx.x * BM;
  const int bn0 = blockIdx.y * BN;
  const int lane = tid & 63;
  const int wave = tid >> 6;
  const int wm = (wave & 1) * 64;
  const int wn = (wave >> 1) * 64;
  const int lr = lane & 15;
  const int kg = lane >> 4;
  const int srow = tid >> 1, sch = tid & 1;

  f32x4 acc[4][4] = {};

  for (int k0 = 0; k0 < K; k0 += BK) {
    {
      const u16* gp = A + (size_t)(bm0 + srow) * K + k0 + sch * 16;
      u16* lp = &As[srow * LDT + sch * 16];
      if (k0 + BK <= K) {
        *(uint4*)lp = *(const uint4*)gp;
        *(uint4*)(lp + 8) = *(const uint4*)(gp + 8);
      } else {
        for (int i = 0; i < 16; ++i) {
          int k = k0 + sch * 16 + i;
          lp[i] = (k < K) ? gp[i] : (u16)0;
        }
      }
    }
    {
      const u16* gp = B + (size_t)(bn0 + srow) * K + k0 + sch * 16;
      u16* lp = &Bs[srow * LDT + sch * 16];
      if (k0 + BK <= K) {
        *(uint4*)lp = *(const uint4*)gp;
        *(uint4*)(lp + 8) = *(const uint4*)(gp + 8);
      } else {
        for (int i = 0; i < 16; ++i) {
          int k = k0 + sch * 16 + i;
          lp[i] = (k < K) ? gp[i] : (u16)0;
        }
      }
    }
    __syncthreads();

    h8 af[4], bfr[4];
#pragma unroll
    for (int mi = 0; mi < 4; ++mi)
      af[mi] = *(const h8*)&As[(wm + mi * 16 + lr) * LDT + kg * 8];
#pragma unroll
    for (int ni = 0; ni < 4; ++ni)
      bfr[ni] = *(const h8*)&Bs[(wn + ni * 16 + lr) * LDT + kg * 8];
#pragma unroll
    for (int mi = 0; mi < 4; ++mi)
#pragma unroll
      for (int ni = 0; ni < 4; ++ni)
        acc[mi][ni] = __builtin_amdgcn_mfma_f32_16x16x32_f16(af[mi], bfr[ni], acc[mi][ni], 0, 0, 0);
    __syncthreads();
  }

  // epilogue: D mapping col=lane&15, row=(lane>>4)*4+reg  [m89/m91 verified]
#pragma unroll
  for (int mi = 0; mi < 4; ++mi)
#pragma unroll
    for (int ni = 0; ni < 4; ++ni) {
      int m0 = bm0 + wm + mi * 16 + kg * 4;
      int col = bn0 + wn + ni * 16 + lr;
      float bv = bias ? bias[col] : 0.f;
      if (MODE == 2) {
        int bidx = m0 >> 10, t0 = m0 & 1023;
        u16x4 pk;
#pragma unroll
        for (int r = 0; r < 4; ++r) pk[r] = f2h((acc[mi][ni][r] + bv) * scale);
        *(u16x4*)((u16*)Cout + (size_t)bidx * N * Tn + (size_t)col * Tn + t0) = pk;
      } else {
#pragma unroll
        for (int r = 0; r < 4; ++r) {
          float v = (acc[mi][ni][r] + bv) * scale;
          if (MODE == 1)
            ((u16*)Cout)[(size_t)(m0 + r) * N + col] = f2h(v);
          else
            ((float*)Cout)[(size_t)(m0 + r) * N + col] = v;
        }
      }
    }
}

// ---------- mega kernel: quad-owns-element int8 GRU (blocks 0..63) + riders ----------
// R13 structure: 1024 threads (16 waves, 4/SIMD). Quad j = tid>>2 owns element j:
// lane q = tid&3 covers k-quarter q for rows {j, j+256, j+512} (48 sdot4).
// After 3 quad-reduces ALL lanes hold gr/gz/gn for j -> gate computed inline
// (no ght buffer, no second barrier). h double-buffered in LDS (dot reads buf rp,
// gate writes buf rp^1) -> ONE barrier per step, race-free.
__global__ void __launch_bounds__(1024)
__attribute__((amdgpu_waves_per_eu(4, 4)))
k_mega(const u32* __restrict__ Wp8, const float* __restrict__ wscGh,
       const float* __restrict__ bhh,
       u16* __restrict__ xgT, u16* __restrict__ o, float* __restrict__ hst,
       int gruH,
       const u16* __restrict__ gA, const u16* __restrict__ gB,
       const float* __restrict__ gBias, float gScale,
       u16* __restrict__ gC, int gmMode, int gmH, int gmN) {
  const int ngru = (gruH >= 0) ? 64 : 0;
  const int tid = threadIdx.x;
  __shared__ __align__(16) char ldsu[20992];   // max(gru 12.8KB, gemm 20.5KB)

  if ((int)blockIdx.x < ngru) {
    // ================= GRU role =================
    char* hsh8 = ldsu;                          // 2 x 256 B (i8 h, double-buffered)
    u16* xst = (u16*)(ldsu + 512);              // 12288 B, [u][j] (f16 bits)
    const int b = blockIdx.x;
    const int j = tid >> 2;                     // owned element
    const int q = tid & 3;                      // k-quarter
    const int qlead = (q == 0);

    u32 wv8[48];
    {
      const uint4* wp = (const uint4*)(Wp8 + (size_t)tid * 48);
#pragma unroll
      for (int i = 0; i < 12; ++i) ((uint4*)wv8)[i] = wp[i];
    }
#pragma unroll
    for (int i = 0; i < 48; ++i) asm volatile("" : "+v"(wv8[i]));

    const float wsc0 = wscGh[j], wsc1 = wscGh[j + Hn], wsc2 = wscGh[j + 2 * Hn];
    const float b0 = bhh[j], b1 = bhh[j + Hn], b2 = bhh[j + 2 * Hn];
    float hreg = (gruH > 0) ? hst[b * Hn + j] : 0.f;
    if (qlead) hsh8[j] = (char)(int)lrintf(hreg * 127.f);

    const u16* xrow = (tid < G3) ? xgT + (size_t)b * G3 * Tn + (size_t)tid * Tn : nullptr;
    u16* ob = o + (size_t)b * Tn * Hn;
    const int tc0 = gruH * 64, tc1 = tc0 + 64;

    uint4 xchunk = {};
    if (tid < G3) xchunk = *(const uint4*)(xrow + tc0 * CH);
    int rp = 0;
    __syncthreads();

    for (int tc = tc0; tc < tc1; ++tc) {
      // stash chunk transposed [u][j] (x-gate rows: threads < 768)
      if (tid < G3) {
#pragma unroll
        for (int u = 0; u < CH; ++u) {
          u32 w = ((u32*)&xchunk)[u >> 1];
          u16 piece = (u & 1) ? (u16)(w >> 16) : (u16)w;
          xst[u * G3 + tid] = piece;
        }
        int tcn = (tc + 1 < Tn / CH) ? tc + 1 : tc;
        xchunk = *(const uint4*)(xrow + tcn * CH);
      }
      lds_barrier();

#pragma unroll
      for (int u = 0; u < CH; ++u) {
        // ---- dot phase: 4 x ds_read_b128 + 48 sdot4 (3 rows x 16) ----
        const uint4* hq4 = (const uint4*)(hsh8 + rp * 256 + q * 64);
        int A0 = 0, A1 = 0, A2 = 0;
#pragma unroll
        for (int i = 0; i < 4; ++i) {
          uint4 hv = hq4[i];
#pragma unroll
          for (int p = 0; p < 4; ++p) {
            u32 hw = (&hv.x)[p];
            A0 = sdot4(wv8[i * 4 + p], hw, A0);
            A1 = sdot4(wv8[16 + i * 4 + p], hw, A1);
            A2 = sdot4(wv8[32 + i * 4 + p], hw, A2);
          }
        }
        A0 = qsumi(A0); A1 = qsumi(A1); A2 = qsumi(A2);
        // ---- inline gate (all lanes of quad redundantly; no barrier needed) ----
        float gr = (float)A0 * wsc0 + b0;
        float gz = (float)A1 * wsc1 + b1;
        float gn = (float)A2 * wsc2 + b2;
        float xr = h2f(xst[u * G3 + j]);
        float xz = h2f(xst[u * G3 + j + Hn]);
        float xn = h2f(xst[u * G3 + j + 2 * Hn]);
        float r = fsig(xr + gr);
        float z = fsig(xz + gz);
        float n = ftanh(xn + r * gn);
        hreg = (1.f - z) * n + z * hreg;
        if (qlead) {
          ob[(size_t)(tc * CH + u) * Hn + j] = f2h(hreg);
          hsh8[(rp ^ 1) * 256 + j] = (char)(int)lrintf(hreg * 127.f);
        }
        lds_barrier();
        rp ^= 1;
      }
    }
    if (qlead) hst[b * Hn + j] = hreg;
    return;
  }

  // ================= GEMM rider (f16 MFMA; threads 0..255 active) =================
  if (gmMode == 0) return;
  constexpr int LDT = 40;
  u16* As = (u16*)ldsu;             // [128*40]
  u16* Bs = (u16*)(ldsu + 10240);   // [128*40]
  const int idx = blockIdx.x - ngru;
  const int mt = idx & 255, nt = idx >> 8;
  const int bm0 = (mt >> 2) * Tn + gmH * 512 + (mt & 3) * 128;
  const int bn0 = nt * 128;
  const int lane = tid & 63;
  const int wave = tid >> 6;
  const int wm = (wave & 1) * 64;
  const int wn = (wave >> 1) * 64;
  const int lr = lane & 15;
  const int kg = lane >> 4;
  const int srow = (tid & 255) >> 1, sch = tid & 1;

  f32x4 acc[4][4] = {};

  for (int k0 = 0; k0 < 256; k0 += 32) {
    if (tid < 256) {
      const u16* gp = gA + (size_t)(bm0 + srow) * 256 + k0 + sch * 16;
      u16* lp = &As[srow * LDT + sch * 16];
      *(uint4*)lp = *(const uint4*)gp;
      *(uint4*)(lp + 8) = *(const uint4*)(gp + 8);
      const u16* gp2 = gB + (size_t)(bn0 + srow) * 256 + k0 + sch * 16;
      u16* lp2 = &Bs[srow * LDT + sch * 16];
      *(uint4*)lp2 = *(const uint4*)gp2;
      *(uint4*)(lp2 + 8) = *(const uint4*)(gp2 + 8);
    }
    __syncthreads();
    if (tid < 256) {
      h8 af[4], bfr[4];
#pragma unroll
      for (int mi = 0; mi < 4; ++mi)
        af[mi] = *(const h8*)&As[(wm + mi * 16 + lr) * LDT + kg * 8];
#pragma unroll
      for (int ni = 0; ni < 4; ++ni)
        bfr[ni] = *(const h8*)&Bs[(wn + ni * 16 + lr) * LDT + kg * 8];
#pragma unroll
      for (int mi = 0; mi < 4; ++mi)
#pragma unroll
        for (int ni = 0; ni < 4; ++ni)
          acc[mi][ni] = __builtin_amdgcn_mfma_f32_16x16x32_f16(af[mi], bfr[ni], acc[mi][ni], 0, 0, 0);
    }
    __syncthreads();
  }

  if (tid < 256) {
#pragma unroll
    for (int mi = 0; mi < 4; ++mi)
#pragma unroll
      for (int ni = 0; ni < 4; ++ni) {
        int m0 = bm0 + wm + mi * 16 + kg * 4;
        int col = bn0 + wn + ni * 16 + lr;
        float bv = gBias[col];
        if (gmMode == 2) {
          int bidx = m0 >> 10, t0 = m0 & 1023;
          u16x4 pk;
#pragma unroll
          for (int r = 0; r < 4; ++r) pk[r] = f2h((acc[mi][ni][r] + bv) * gScale);
          *(u16x4*)(gC + (size_t)bidx * gmN * Tn + (size_t)col * Tn + t0) = pk;
        } else {
#pragma unroll
          for (int r = 0; r < 4; ++r)
            gC[(size_t)(m0 + r) * gmN + col] = f2h((acc[mi][ni][r] + bv) * gScale);
        }
      }
  }
}

// ---------- attention over 5 style tokens (f16 q/ctx) ----------
__global__ __launch_bounds__(256) void k_attn(const u16* __restrict__ q,
                                              const float* __restrict__ kv,
                                              u16* __restrict__ ctx) {
  __shared__ float ks[STOK * Hn], vs[STOK * Hn];
  int tid = threadIdx.x;
  for (int i = tid; i < STOK * Hn; i += 256) {
    ks[i] = kv[i];
    vs[i] = kv[STOK * Hn + i];
  }
  __syncthreads();
  size_t row = (size_t)blockIdx.x * 256 + tid;
  const u16* qr = q + row * Hn;
  u16* cr = ctx + row * Hn;
#pragma unroll
  for (int h = 0; h < 4; ++h) {
    float sc[STOK] = {0.f, 0.f, 0.f, 0.f, 0.f};
    for (int d = 0; d < 64; ++d) {
      float qv = h2f(qr[h * 64 + d]);
#pragma unroll
      for (int s = 0; s < STOK; ++s) sc[s] += qv * ks[s * Hn + h * 64 + d];
    }
    float m = sc[0];
#pragma unroll
    for (int s = 1; s < STOK; ++s) m = fmaxf(m, sc[s]);
    float p[STOK], sum = 0.f;
#pragma unroll
    for (int s = 0; s < STOK; ++s) { p[s] = __expf(sc[s] - m); sum += p[s]; }
    float inv = 1.f / sum;
    for (int e = 0; e < 64; ++e) {
      float c = 0.f;
#pragma unroll
      for (int s = 0; s < STOK; ++s) c += p[s] * vs[s * Hn + h * 64 + e];
      cr[h * 64 + e] = f2h(c * inv);
    }
  }
}

// ---------- workspace layout (bytes) ----------
#define WS_XGT  ((size_t)0)           // [B][768][T] f16 = 100,663,296 (xg0, then xg1 in-place)
#define WS_O    ((size_t)100663296)   // [B][T][256] f16 = 33,554,432 (o0, then o1 in-place)
#define WS_QB   ((size_t)134217728)   // q [B*T][256] f16 = 33,554,432
#define WS_FB   ((size_t)167772160)   // feats f16 = 10,485,760 (hst aliases after head)
#define WS_W0   ((size_t)178257920)   // Wih0 f16 = 122,880
#define WS_W1   ((size_t)178380800)   // Wih1 f16 = 393,216
#define WS_QW   ((size_t)178774016)   // q_w f16 = 131,072
#define WS_OW   ((size_t)178905088)   // out_w f16 = 131,072
#define WS_H0P  ((size_t)179036160)   // Whh0 int8 packed = 196,608
#define WS_H1P  ((size_t)179232768)   // Whh1 int8 packed = 196,608
#define WS_SC0  ((size_t)179429376)   // wscGh0 f32 = 3,072
#define WS_SC1  ((size_t)179432448)   // wscGh1 f32 = 3,072
#define WS_MX0  ((size_t)179435520)   // wmaxraw0 f32 = 3,072
#define WS_MX1  ((size_t)179438592)   // wmaxraw1 f32 = 3,072
#define WS_KV   ((size_t)179822592)   // k,v f32 = 10,240
#define WS_HST  WS_FB                 // h state f32 [64][256] (fb dead after head)
#define WS_CTX  WS_XGT                // ctx [B*T][256] f16 (xgT dead after D4)

extern "C" void kernel_launch(void* const* d_in, const int* in_sizes, int n_in,
                              void* d_out, int out_size, void* d_ws, size_t ws_size,
                              hipStream_t stream) {
  const float* feats = (const float*)d_in[0];
  const float* style = (const float*)d_in[1];
  const float* Wih0 = (const float*)d_in[2];
  const float* Whh0 = (const float*)d_in[3];
  const float* bih0 = (const float*)d_in[4];
  const float* bhh0 = (const float*)d_in[5];
  const float* Wih1 = (const float*)d_in[6];
  const float* Whh1 = (const float*)d_in[7];
  const float* bih1 = (const float*)d_in[8];
  const float* bhh1 = (const float*)d_in[9];
  const float* q_w = (const float*)d_in[10];
  const float* k_w = (const float*)d_in[11];
  const float* v_w = (const float*)d_in[12];
  const float* in_b = (const float*)d_in[13];
  const float* out_w = (const float*)d_in[14];
  const float* out_b = (const float*)d_in[15];

  char* ws = (char*)d_ws;
  u16* xgT = (u16*)(ws + WS_XGT);
  u16* o = (u16*)(ws + WS_O);
  u16* qb = (u16*)(ws + WS_QB);
  u16* fb = (u16*)(ws + WS_FB);
  u16* w0 = (u16*)(ws + WS_W0);
  u16* w1 = (u16*)(ws + WS_W1);
  u16* qw = (u16*)(ws + WS_QW);
  u16* ow = (u16*)(ws + WS_OW);
  u32* h0p = (u32*)(ws + WS_H0P);
  u32* h1p = (u32*)(ws + WS_H1P);
  float* sc0 = (float*)(ws + WS_SC0);
  float* sc1 = (float*)(ws + WS_SC1);
  float* mx0 = (float*)(ws + WS_MX0);
  float* mx1 = (float*)(ws + WS_MX1);
  float* kv = (float*)(ws + WS_KV);
  float* hst = (float*)(ws + WS_HST);
  u16* ctx = (u16*)(ws + WS_CTX);

  auto cvgrid = [](int n) { int g = (n + 255) / 256; return g > 2048 ? 2048 : g; };

  // ---- head: conversions, weight prep, kv, xg0 GEMM ----
  k_cvt_f16<<<cvgrid(MROWS * IDIM), 256, 0, stream>>>(feats, fb, MROWS * IDIM);
  k_cvt_f16<<<cvgrid(G3 * IDIM), 256, 0, stream>>>(Wih0, w0, G3 * IDIM);
  k_cvt_f16<<<cvgrid(G3 * Hn), 256, 0, stream>>>(Wih1, w1, G3 * Hn);
  k_cvt_f16<<<cvgrid(Hn * Hn), 256, 0, stream>>>(q_w, qw, Hn * Hn);
  k_cvt_f16<<<cvgrid(Hn * Hn), 256, 0, stream>>>(out_w, ow, Hn * Hn);
  k_wmax<<<3, 256, 0, stream>>>(Whh0, mx0, sc0);
  k_wmax<<<3, 256, 0, stream>>>(Whh1, mx1, sc1);
  k_prep_i8<<<(1024 * 48 + 255) / 256, 256, 0, stream>>>(Whh0, mx0, h0p);
  k_prep_i8<<<(1024 * 48 + 255) / 256, 256, 0, stream>>>(Whh1, mx1, h1p);
  k_kv<<<1, 256, 0, stream>>>(style, k_w, v_w, in_b, kv);

  dim3 g768(MROWS / 128, G3 / 128);
  k_gemm_bt<2><<<g768, 256, 0, stream>>>(fb, w0, bih0, 1.f, xgT, MROWS, G3, IDIM);

  // ---- pipelined halves: gru + co-dispatched GEMM riders ----
  k_mega<<<64, 1024, 0, stream>>>(h0p, sc0, bhh0, xgT, o, hst, 0,
                                  nullptr, nullptr, nullptr, 0.f, nullptr, 0, 0, 0);
  k_mega<<<64 + 1536, 1024, 0, stream>>>(h0p, sc0, bhh0, xgT, o, hst, 1,
                                         o, w1, bih1, 1.f, xgT, 2, 0, G3);
  k_mega<<<64 + 1536, 1024, 0, stream>>>(h1p, sc1, bhh1, xgT, o, hst, 0,
                                         o, w1, bih1, 1.f, xgT, 2, 1, G3);
  k_mega<<<64 + 512, 1024, 0, stream>>>(h1p, sc1, bhh1, xgT, o, hst, 1,
                                        o, qw, in_b, 0.125f, qb, 1, 0, Hn);
  k_mega<<<512, 1024, 0, stream>>>(h0p, sc0, bhh0, xgT, o, hst, -1,
                                   o, qw, in_b, 0.125f, qb, 1, 1, Hn);

  // ---- tail: attention + output projection ----
  k_attn<<<MROWS / 256, 256, 0, stream>>>(qb, kv, ctx);
  dim3 g256t(MROWS / 128, Hn / 128);
  k_gemm_bt<0><<<g256t, 256, 0, stream>>>(ctx, ow, out_b, 1.f, d_out, MROWS, Hn, Hn);
}

// Round 14
// 1842.650 us; speedup vs baseline: 1.0987x; 1.0987x over previous
//
#include <hip/hip_runtime.h>
#include <hip/hip_bf16.h>
#include <cmath>

typedef unsigned int u32;
typedef unsigned short u16;
typedef _Float16 f16;
typedef f16 h2 __attribute__((ext_vector_type(2)));
typedef f16 h8 __attribute__((ext_vector_type(8)));
typedef float f32x4 __attribute__((ext_vector_type(4)));
typedef u16 u16x4 __attribute__((ext_vector_type(4)));

// ---------- sizes ----------
#define Bn 64
#define Tn 1024
#define IDIM 80
#define Hn 256
#define G3 768           // 3*H
#define STOK 5
#define SDIM 128
#define MROWS (Bn*Tn)    // 65536
#define CH 8             // steps per x-chunk

// ---------- helpers ----------
__device__ __forceinline__ u16 f2h(float f) {
  union { f16 h; u16 u; } c; c.h = (f16)f; return c.u;
}
__device__ __forceinline__ float h2f(u16 u) {
  union { f16 h; u16 u2; } c; c.u2 = u; return (float)c.h;
}
__device__ __forceinline__ float frcp(float x) {
#if __has_builtin(__builtin_amdgcn_rcpf)
  return __builtin_amdgcn_rcpf(x);
#else
  return 1.f / x;
#endif
}
__device__ __forceinline__ float fsig(float x) { return frcp(1.f + __expf(-x)); }
__device__ __forceinline__ float ftanh(float x) { return 1.f - 2.f * frcp(1.f + __expf(2.f * x)); }
// int8 dot4: c += sum of 4 signed-byte products
__device__ __forceinline__ int sdot4(u32 a, u32 b, int c) {
#if __has_builtin(__builtin_amdgcn_sdot4)
  return __builtin_amdgcn_sdot4(a, b, c, false);
#else
  int r = c;
#pragma unroll
  for (int j = 0; j < 4; ++j)
    r += (int)(char)(a >> (8 * j)) * (int)(char)(b >> (8 * j));
  return r;
#endif
}
// quad (4-lane) int sum via DPP quad_perm
__device__ __forceinline__ int qsumi(int v) {
  v += __builtin_amdgcn_mov_dpp(v, 0xB1, 0xF, 0xF, true); // xor 1
  v += __builtin_amdgcn_mov_dpp(v, 0x4E, 0xF, 0xF, true); // xor 2
  return v;
}

// LDS-only barrier: raw s_barrier so in-flight global ops survive.
__device__ __forceinline__ void lds_barrier() {
  asm volatile("s_waitcnt lgkmcnt(0)" ::: "memory");
  __builtin_amdgcn_sched_barrier(0);
  __builtin_amdgcn_s_barrier();
  __builtin_amdgcn_sched_barrier(0);
}

// ---------- conversion / prep ----------
__global__ void k_cvt_f16(const float* __restrict__ in, u16* __restrict__ out, int n) {
  int i = blockIdx.x * blockDim.x + threadIdx.x;
  int st = gridDim.x * blockDim.x;
  for (; i < n; i += st) out[i] = f2h(in[i]);
}

// per-row absmax of Whh[768][256]; wmax[j] = m, wsc[j] = m/(127*127)
__global__ void k_wmax(const float* __restrict__ W, float* __restrict__ wmax,
                       float* __restrict__ wsc) {
  int j = blockIdx.x * 256 + threadIdx.x;
  if (j >= G3) return;
  float m = 0.f;
  for (int k = 0; k < Hn; ++k) m = fmaxf(m, fabsf(W[j * Hn + k]));
  wmax[j] = m;
  wsc[j] = m * (1.f / 16129.f);
}

// Pack Whh -> int8 quad-slice (bank-fix layout), 4 k-bytes per u32:
// out[tau*64 + s*16 + i4p] = bytes W[4*(tau>>2)+s][64*(tau&3)+i4p*4 .. +3]
__global__ void k_prep_i8(const float* __restrict__ W, const float* __restrict__ wmax,
                          u32* __restrict__ out) {
  int idx = blockIdx.x * 256 + threadIdx.x;
  if (idx >= G3 * 64) return;
  int tau = idx >> 6, rest = idx & 63;
  int s = rest >> 4, i4p = rest & 15;
  int r = 4 * (tau >> 2) + s;
  int c0 = 64 * (tau & 3) + i4p * 4;
  float m = wmax[r];
  float inv = (m > 0.f) ? (127.f / m) : 0.f;
  u32 pk = 0;
#pragma unroll
  for (int j = 0; j < 4; ++j) {
    int q = (int)lrintf(W[r * Hn + c0 + j] * inv);
    q = (q > 127) ? 127 : (q < -127) ? -127 : q;
    pk |= ((u32)(unsigned char)(char)q) << (8 * j);
  }
  out[idx] = pk;
}

// ---------- k/v projection (f32) ----------
__global__ __launch_bounds__(256) void k_kv(const float* __restrict__ st,
                                            const float* __restrict__ kw,
                                            const float* __restrict__ vw,
                                            const float* __restrict__ inb,
                                            float* __restrict__ kv) {
  int e = threadIdx.x;
  for (int s = 0; s < STOK; ++s) {
    float ak = inb[Hn + e], av = inb[2 * Hn + e];
    for (int d = 0; d < SDIM; ++d) {
      float x = st[s * SDIM + d];
      ak += x * kw[e * SDIM + d];
      av += x * vw[e * SDIM + d];
    }
    kv[s * Hn + e] = ak;
    kv[STOK * Hn + s * Hn + e] = av;
  }
}

// ---------- standalone f16 MFMA GEMM: C = scale*(A @ B^T + bias) ----------
// MODE 0: f32 out [M][N]; 1: f16 out [M][N]; 2: f16 out TRANSPOSED [B][N][T]
template <int MODE>
__global__ __launch_bounds__(256) void k_gemm_bt(const u16* __restrict__ A,
                                                 const u16* __restrict__ B,
                                                 const float* __restrict__ bias,
                                                 float scale, void* __restrict__ Cout,
                                                 int M, int N, int K) {
  constexpr int BM = 128, BN = 128, BK = 32, LDT = 40;
  __shared__ __align__(16) u16 As[BM * LDT];
  __shared__ __align__(16) u16 Bs[BN * LDT];
  const int tid = threadIdx.x;
  const int bm0 = blockIdx.x * BM;
  const int bn0 = blockIdx.y * BN;
  const int lane = tid & 63;
  const int wave = tid >> 6;
  const int wm = (wave & 1) * 64;
  const int wn = (wave >> 1) * 64;
  const int lr = lane & 15;
  const int kg = lane >> 4;
  const int srow = tid >> 1, sch = tid & 1;

  f32x4 acc[4][4] = {};

  for (int k0 = 0; k0 < K; k0 += BK) {
    {
      const u16* gp = A + (size_t)(bm0 + srow) * K + k0 + sch * 16;
      u16* lp = &As[srow * LDT + sch * 16];
      if (k0 + BK <= K) {
        *(uint4*)lp = *(const uint4*)gp;
        *(uint4*)(lp + 8) = *(const uint4*)(gp + 8);
      } else {
        for (int i = 0; i < 16; ++i) {
          int k = k0 + sch * 16 + i;
          lp[i] = (k < K) ? gp[i] : (u16)0;
        }
      }
    }
    {
      const u16* gp = B + (size_t)(bn0 + srow) * K + k0 + sch * 16;
      u16* lp = &Bs[srow * LDT + sch * 16];
      if (k0 + BK <= K) {
        *(uint4*)lp = *(const uint4*)gp;
        *(uint4*)(lp + 8) = *(const uint4*)(gp + 8);
      } else {
        for (int i = 0; i < 16; ++i) {
          int k = k0 + sch * 16 + i;
          lp[i] = (k < K) ? gp[i] : (u16)0;
        }
      }
    }
    __syncthreads();

    h8 af[4], bfr[4];
#pragma unroll
    for (int mi = 0; mi < 4; ++mi)
      af[mi] = *(const h8*)&As[(wm + mi * 16 + lr) * LDT + kg * 8];
#pragma unroll
    for (int ni = 0; ni < 4; ++ni)
      bfr[ni] = *(const h8*)&Bs[(wn + ni * 16 + lr) * LDT + kg * 8];
#pragma unroll
    for (int mi = 0; mi < 4; ++mi)
#pragma unroll
      for (int ni = 0; ni < 4; ++ni)
        acc[mi][ni] = __builtin_amdgcn_mfma_f32_16x16x32_f16(af[mi], bfr[ni], acc[mi][ni], 0, 0, 0);
    __syncthreads();
  }

  // epilogue: D mapping col=lane&15, row=(lane>>4)*4+reg  [m89/m91 verified]
#pragma unroll
  for (int mi = 0; mi < 4; ++mi)
#pragma unroll
    for (int ni = 0; ni < 4; ++ni) {
      int m0 = bm0 + wm + mi * 16 + kg * 4;
      int col = bn0 + wn + ni * 16 + lr;
      float bv = bias ? bias[col] : 0.f;
      if (MODE == 2) {
        int bidx = m0 >> 10, t0 = m0 & 1023;
        u16x4 pk;
#pragma unroll
        for (int r = 0; r < 4; ++r) pk[r] = f2h((acc[mi][ni][r] + bv) * scale);
        *(u16x4*)((u16*)Cout + (size_t)bidx * N * Tn + (size_t)col * Tn + t0) = pk;
      } else {
#pragma unroll
        for (int r = 0; r < 4; ++r) {
          float v = (acc[mi][ni][r] + bv) * scale;
          if (MODE == 1)
            ((u16*)Cout)[(size_t)(m0 + r) * N + col] = f2h(v);
          else
            ((float*)Cout)[(size_t)(m0 + r) * N + col] = v;
        }
      }
    }
}

// ---------- mega kernel: int8 GRU half-scan (blocks 0..63) + f16 GEMM riders ----------
// R11 form (best measured). GRU dot core: int8 sdot4. Thread tau: quarter
// q=tau&3 of k, rows {4*(tau>>2)+s}; W int8 register-resident (64 u32).
// h quantized to i8 in LDS; gh = int-dot x wmax_row/127^2 (exact int accumulate
// + int DPP quad-reduce). 64 sdot4 + 4 ds_read_b128 per thread per step.
// Gate on waves 0-3 (serial variant measured fastest vs R12/R13 alternatives).
__global__ void __launch_bounds__(768)
__attribute__((amdgpu_waves_per_eu(3, 3)))
k_mega(const u32* __restrict__ Wp8, const float* __restrict__ wscGh,
       const float* __restrict__ bhh,
       u16* __restrict__ xgT, u16* __restrict__ o, float* __restrict__ hst,
       int gruH,
       const u16* __restrict__ gA, const u16* __restrict__ gB,
       const float* __restrict__ gBias, float gScale,
       u16* __restrict__ gC, int gmMode, int gmH, int gmN) {
  const int ngru = (gruH >= 0) ? 64 : 0;
  const int tid = threadIdx.x;
  __shared__ __align__(16) char ldsu[20992];   // max(gru 15.6KB, gemm 20.5KB)

  if ((int)blockIdx.x < ngru) {
    // ================= GRU role =================
    char* hsh8 = ldsu;                          // 256 B (i8 h)
    float* ght = (float*)(ldsu + 256);          // 3072 B
    u16* xst = (u16*)(ldsu + 256 + 3072);       // 12288 B, [u][j] (f16 bits)
    const int b = blockIdx.x;

    u32 wv8[64];
    {
      const uint4* wp = (const uint4*)(Wp8 + (size_t)tid * 64);
#pragma unroll
      for (int i = 0; i < 16; ++i) ((uint4*)wv8)[i] = wp[i];
    }
#pragma unroll
    for (int i = 0; i < 64; ++i) asm volatile("" : "+v"(wv8[i]));
    const float wsc = wscGh[tid];

    float b0 = 0.f, b1 = 0.f, b2 = 0.f;
    float hreg = 0.f;
    if (tid < Hn) {
      b0 = bhh[tid]; b1 = bhh[tid + Hn]; b2 = bhh[tid + 2 * Hn];
      if (gruH > 0) hreg = hst[b * Hn + tid];
      hsh8[tid] = (char)(int)lrintf(hreg * 127.f);
    }

    const u16* xrow = xgT + (size_t)b * G3 * Tn + (size_t)tid * Tn;
    u16* ob = o + (size_t)b * Tn * Hn;
    const uint4* hq4 = (const uint4*)(hsh8 + (tid & 3) * 64);
    const int tc0 = gruH * 64, tc1 = tc0 + 64;

    uint4 xchunk = *(const uint4*)(xrow + tc0 * CH);
    __syncthreads();

    for (int tc = tc0; tc < tc1; ++tc) {
      // stash chunk transposed [u][j]
#pragma unroll
      for (int u = 0; u < CH; ++u) {
        u32 w = ((u32*)&xchunk)[u >> 1];
        u16 piece = (u & 1) ? (u16)(w >> 16) : (u16)w;
        xst[u * G3 + tid] = piece;
      }
      int tcn = (tc + 1 < Tn / CH) ? tc + 1 : tc;
      xchunk = *(const uint4*)(xrow + tcn * CH);

#pragma unroll
      for (int u = 0; u < CH; ++u) {
        // ---- dot phase: 4 x ds_read_b128 + 64 sdot4 ----
        int A0 = 0, A1 = 0, A2 = 0, A3 = 0;
#pragma unroll
        for (int i = 0; i < 4; ++i) {
          uint4 hv = hq4[i];
#pragma unroll
          for (int p = 0; p < 4; ++p) {
            u32 hw = (&hv.x)[p];
            A0 = sdot4(wv8[i * 4 + p], hw, A0);
            A1 = sdot4(wv8[16 + i * 4 + p], hw, A1);
            A2 = sdot4(wv8[32 + i * 4 + p], hw, A2);
            A3 = sdot4(wv8[48 + i * 4 + p], hw, A3);
          }
        }
        A0 = qsumi(A0); A1 = qsumi(A1); A2 = qsumi(A2); A3 = qsumi(A3);
        int q = tid & 3;
        int isel = (q == 0) ? A0 : (q == 1) ? A1 : (q == 2) ? A2 : A3;
        ght[tid] = (float)isel * wsc;   // row == tid (bank-fix mapping)
        lds_barrier();
        // ---- gate phase (waves 0-3) ----
        if (tid < Hn) {
          float gr = ght[tid] + b0;
          float gz = ght[tid + Hn] + b1;
          float gn = ght[tid + 2 * Hn] + b2;
          float xr = h2f(xst[u * G3 + tid]);
          float xz = h2f(xst[u * G3 + tid + Hn]);
          float xn = h2f(xst[u * G3 + tid + 2 * Hn]);
          float r = fsig(xr + gr);
          float z = fsig(xz + gz);
          float n = ftanh(xn + r * gn);
          hreg = (1.f - z) * n + z * hreg;
          ob[(size_t)(tc * CH + u) * Hn + tid] = f2h(hreg);
          hsh8[tid] = (char)(int)lrintf(hreg * 127.f);
        }
        lds_barrier();
      }
    }
    if (tid < Hn) hst[b * Hn + tid] = hreg;
    return;
  }

  // ================= GEMM rider (f16 MFMA) =================
  if (gmMode == 0) return;
  constexpr int LDT = 40;
  u16* As = (u16*)ldsu;             // [128*40]
  u16* Bs = (u16*)(ldsu + 10240);   // [128*40]
  const int idx = blockIdx.x - ngru;
  const int mt = idx & 255, nt = idx >> 8;
  const int bm0 = (mt >> 2) * Tn + gmH * 512 + (mt & 3) * 128;
  const int bn0 = nt * 128;
  const int lane = tid & 63;
  const int wave = tid >> 6;
  const int wm = (wave & 1) * 64;
  const int wn = (wave >> 1) * 64;
  const int lr = lane & 15;
  const int kg = lane >> 4;
  const int srow = (tid & 255) >> 1, sch = tid & 1;

  f32x4 acc[4][4] = {};

  for (int k0 = 0; k0 < 256; k0 += 32) {
    if (tid < 256) {
      const u16* gp = gA + (size_t)(bm0 + srow) * 256 + k0 + sch * 16;
      u16* lp = &As[srow * LDT + sch * 16];
      *(uint4*)lp = *(const uint4*)gp;
      *(uint4*)(lp + 8) = *(const uint4*)(gp + 8);
      const u16* gp2 = gB + (size_t)(bn0 + srow) * 256 + k0 + sch * 16;
      u16* lp2 = &Bs[srow * LDT + sch * 16];
      *(uint4*)lp2 = *(const uint4*)gp2;
      *(uint4*)(lp2 + 8) = *(const uint4*)(gp2 + 8);
    }
    __syncthreads();
    if (tid < 256) {
      h8 af[4], bfr[4];
#pragma unroll
      for (int mi = 0; mi < 4; ++mi)
        af[mi] = *(const h8*)&As[(wm + mi * 16 + lr) * LDT + kg * 8];
#pragma unroll
      for (int ni = 0; ni < 4; ++ni)
        bfr[ni] = *(const h8*)&Bs[(wn + ni * 16 + lr) * LDT + kg * 8];
#pragma unroll
      for (int mi = 0; mi < 4; ++mi)
#pragma unroll
        for (int ni = 0; ni < 4; ++ni)
          acc[mi][ni] = __builtin_amdgcn_mfma_f32_16x16x32_f16(af[mi], bfr[ni], acc[mi][ni], 0, 0, 0);
    }
    __syncthreads();
  }

  if (tid < 256) {
#pragma unroll
    for (int mi = 0; mi < 4; ++mi)
#pragma unroll
      for (int ni = 0; ni < 4; ++ni) {
        int m0 = bm0 + wm + mi * 16 + kg * 4;
        int col = bn0 + wn + ni * 16 + lr;
        float bv = gBias[col];
        if (gmMode == 2) {
          int bidx = m0 >> 10, t0 = m0 & 1023;
          u16x4 pk;
#pragma unroll
          for (int r = 0; r < 4; ++r) pk[r] = f2h((acc[mi][ni][r] + bv) * gScale);
          *(u16x4*)(gC + (size_t)bidx * gmN * Tn + (size_t)col * Tn + t0) = pk;
        } else {
#pragma unroll
          for (int r = 0; r < 4; ++r)
            gC[(size_t)(m0 + r) * gmN + col] = f2h((acc[mi][ni][r] + bv) * gScale);
        }
      }
  }
}

// ---------- attention over 5 style tokens (f16 q/ctx) ----------
__global__ __launch_bounds__(256) void k_attn(const u16* __restrict__ q,
                                              const float* __restrict__ kv,
                                              u16* __restrict__ ctx) {
  __shared__ float ks[STOK * Hn], vs[STOK * Hn];
  int tid = threadIdx.x;
  for (int i = tid; i < STOK * Hn; i += 256) {
    ks[i] = kv[i];
    vs[i] = kv[STOK * Hn + i];
  }
  __syncthreads();
  size_t row = (size_t)blockIdx.x * 256 + tid;
  const u16* qr = q + row * Hn;
  u16* cr = ctx + row * Hn;
#pragma unroll
  for (int h = 0; h < 4; ++h) {
    float sc[STOK] = {0.f, 0.f, 0.f, 0.f, 0.f};
    for (int d = 0; d < 64; ++d) {
      float qv = h2f(qr[h * 64 + d]);
#pragma unroll
      for (int s = 0; s < STOK; ++s) sc[s] += qv * ks[s * Hn + h * 64 + d];
    }
    float m = sc[0];
#pragma unroll
    for (int s = 1; s < STOK; ++s) m = fmaxf(m, sc[s]);
    float p[STOK], sum = 0.f;
#pragma unroll
    for (int s = 0; s < STOK; ++s) { p[s] = __expf(sc[s] - m); sum += p[s]; }
    float inv = 1.f / sum;
    for (int e = 0; e < 64; ++e) {
      float c = 0.f;
#pragma unroll
      for (int s = 0; s < STOK; ++s) c += p[s] * vs[s * Hn + h * 64 + e];
      cr[h * 64 + e] = f2h(c * inv);
    }
  }
}

// ---------- workspace layout (bytes) ----------
#define WS_XGT  ((size_t)0)           // [B][768][T] f16 = 100,663,296 (xg0, then xg1 in-place)
#define WS_O    ((size_t)100663296)   // [B][T][256] f16 = 33,554,432 (o0, then o1 in-place)
#define WS_QB   ((size_t)134217728)   // q [B*T][256] f16 = 33,554,432
#define WS_FB   ((size_t)167772160)   // feats f16 = 10,485,760 (hst aliases after head)
#define WS_W0   ((size_t)178257920)   // Wih0 f16 = 122,880
#define WS_W1   ((size_t)178380800)   // Wih1 f16 = 393,216
#define WS_QW   ((size_t)178774016)   // q_w f16 = 131,072
#define WS_OW   ((size_t)178905088)   // out_w f16 = 131,072
#define WS_H0P  ((size_t)179036160)   // Whh0 int8 packed = 196,608
#define WS_H1P  ((size_t)179232768)   // Whh1 int8 packed = 196,608
#define WS_SC0  ((size_t)179429376)   // wscGh0 f32 = 3,072
#define WS_SC1  ((size_t)179432448)   // wscGh1 f32 = 3,072
#define WS_MX0  ((size_t)179435520)   // wmaxraw0 f32 = 3,072
#define WS_MX1  ((size_t)179438592)   // wmaxraw1 f32 = 3,072
#define WS_KV   ((size_t)179822592)   // k,v f32 = 10,240
#define WS_HST  WS_FB                 // h state f32 [64][256] (fb dead after head)
#define WS_CTX  WS_XGT                // ctx [B*T][256] f16 (xgT dead after D4)

extern "C" void kernel_launch(void* const* d_in, const int* in_sizes, int n_in,
                              void* d_out, int out_size, void* d_ws, size_t ws_size,
                              hipStream_t stream) {
  const float* feats = (const float*)d_in[0];
  const float* style = (const float*)d_in[1];
  const float* Wih0 = (const float*)d_in[2];
  const float* Whh0 = (const float*)d_in[3];
  const float* bih0 = (const float*)d_in[4];
  const float* bhh0 = (const float*)d_in[5];
  const float* Wih1 = (const float*)d_in[6];
  const float* Whh1 = (const float*)d_in[7];
  const float* bih1 = (const float*)d_in[8];
  const float* bhh1 = (const float*)d_in[9];
  const float* q_w = (const float*)d_in[10];
  const float* k_w = (const float*)d_in[11];
  const float* v_w = (const float*)d_in[12];
  const float* in_b = (const float*)d_in[13];
  const float* out_w = (const float*)d_in[14];
  const float* out_b = (const float*)d_in[15];

  char* ws = (char*)d_ws;
  u16* xgT = (u16*)(ws + WS_XGT);
  u16* o = (u16*)(ws + WS_O);
  u16* qb = (u16*)(ws + WS_QB);
  u16* fb = (u16*)(ws + WS_FB);
  u16* w0 = (u16*)(ws + WS_W0);
  u16* w1 = (u16*)(ws + WS_W1);
  u16* qw = (u16*)(ws + WS_QW);
  u16* ow = (u16*)(ws + WS_OW);
  u32* h0p = (u32*)(ws + WS_H0P);
  u32* h1p = (u32*)(ws + WS_H1P);
  float* sc0 = (float*)(ws + WS_SC0);
  float* sc1 = (float*)(ws + WS_SC1);
  float* mx0 = (float*)(ws + WS_MX0);
  float* mx1 = (float*)(ws + WS_MX1);
  float* kv = (float*)(ws + WS_KV);
  float* hst = (float*)(ws + WS_HST);
  u16* ctx = (u16*)(ws + WS_CTX);

  auto cvgrid = [](int n) { int g = (n + 255) / 256; return g > 2048 ? 2048 : g; };

  // ---- head: conversions, weight prep, kv, xg0 GEMM ----
  k_cvt_f16<<<cvgrid(MROWS * IDIM), 256, 0, stream>>>(feats, fb, MROWS * IDIM);
  k_cvt_f16<<<cvgrid(G3 * IDIM), 256, 0, stream>>>(Wih0, w0, G3 * IDIM);
  k_cvt_f16<<<cvgrid(G3 * Hn), 256, 0, stream>>>(Wih1, w1, G3 * Hn);
  k_cvt_f16<<<cvgrid(Hn * Hn), 256, 0, stream>>>(q_w, qw, Hn * Hn);
  k_cvt_f16<<<cvgrid(Hn * Hn), 256, 0, stream>>>(out_w, ow, Hn * Hn);
  k_wmax<<<3, 256, 0, stream>>>(Whh0, mx0, sc0);
  k_wmax<<<3, 256, 0, stream>>>(Whh1, mx1, sc1);
  k_prep_i8<<<(G3 * 64 + 255) / 256, 256, 0, stream>>>(Whh0, mx0, h0p);
  k_prep_i8<<<(G3 * 64 + 255) / 256, 256, 0, stream>>>(Whh1, mx1, h1p);
  k_kv<<<1, 256, 0, stream>>>(style, k_w, v_w, in_b, kv);

  dim3 g768(MROWS / 128, G3 / 128);
  k_gemm_bt<2><<<g768, 256, 0, stream>>>(fb, w0, bih0, 1.f, xgT, MROWS, G3, IDIM);

  // ---- pipelined halves: gru + co-dispatched GEMM riders ----
  k_mega<<<64, 768, 0, stream>>>(h0p, sc0, bhh0, xgT, o, hst, 0,
                                 nullptr, nullptr, nullptr, 0.f, nullptr, 0, 0, 0);
  k_mega<<<64 + 1536, 768, 0, stream>>>(h0p, sc0, bhh0, xgT, o, hst, 1,
                                        o, w1, bih1, 1.f, xgT, 2, 0, G3);
  k_mega<<<64 + 1536, 768, 0, stream>>>(h1p, sc1, bhh1, xgT, o, hst, 0,
                                        o, w1, bih1, 1.f, xgT, 2, 1, G3);
  k_mega<<<64 + 512, 768, 0, stream>>>(h1p, sc1, bhh1, xgT, o, hst, 1,
                                       o, qw, in_b, 0.125f, qb, 1, 0, Hn);
  k_mega<<<512, 768, 0, stream>>>(h0p, sc0, bhh0, xgT, o, hst, -1,
                                  o, qw, in_b, 0.125f, qb, 1, 1, Hn);

  // ---- tail: attention + output projection ----
  k_attn<<<MROWS / 256, 256, 0, stream>>>(qb, kv, ctx);
  dim3 g256t(MROWS / 128, Hn / 128);
  k_gemm_bt<0><<<g256t, 256, 0, stream>>>(ctx, ow, out_b, 1.f, d_out, MROWS, Hn, Hn);
}